// Round 8
// baseline (223.037 us; speedup 1.0000x reference)
//
#include <hip/hip_runtime.h>
#include <hip/hip_bf16.h>
#include <cstdint>

#define BB 64
#define TT 200
#define KN 2000
#define VV 128

typedef __attribute__((ext_vector_type(8))) short bf16x8;
typedef __attribute__((ext_vector_type(4))) float f32x4;
typedef __attribute__((ext_vector_type(16))) float f32x16;

// ws layout (floats): pd[384]@0, pr[384]@384, uc[128]@768, ud[128]@896, ur[128]@1024

__device__ __forceinline__ float sigm(float x) { return 1.f / (1.f + __expf(-x)); }
__device__ __forceinline__ float tanh_f(float x) {
    float e = __expf(2.f * x);
    return (e - 1.f) / (e + 1.f);
}

// ---------------- precompute: small projection vectors ----------
__global__ void pre_kernel(const float* __restrict__ v_d, const float* __restrict__ v_r,
                           const float* __restrict__ v_c, const float* __restrict__ W_ih,
                           const float* __restrict__ W2a, float* __restrict__ ws)
{
    int g = blockIdx.x * 256 + threadIdx.x;   // grid 2 x 256 = 512 threads
    float* pd = ws;
    float* pr = ws + 384;
    float* uc = ws + 768;
    float* ud = ws + 896;
    float* ur = ws + 1024;
    if (g < 384) {
        float a = 0.f, b = 0.f;
        for (int k = 0; k < VV; ++k) {
            a = fmaf(W_ih[g * 256 + k], v_d[k], a);
            b = fmaf(W_ih[g * 256 + VV + k], v_r[k], b);
        }
        pd[g] = a; pr[g] = b;
    }
    if (g < VV) {
        float a = 0.f, b = 0.f, c = 0.f;
        for (int k = 0; k < VV; ++k) {
            a = fmaf(W2a[g * 384 + k], v_c[k], a);
            b = fmaf(W2a[g * 384 + VV + k], v_d[k], b);
            c = fmaf(W2a[g * 384 + 2 * VV + k], v_r[k], c);
        }
        uc[g] = a; ud[g] = b; ur[g] = c;
    }
}

// ---------------- fused: blocks 0-63 GRU scan, blocks 64-127 memory scan + C_out
// GRU restructure (r7 lesson: 2184 cy/step was LDS-issue + barrier-width bound):
// 8 waves (512 thr). wave w: jg=w>>2 (j-base jg*192), kg=w&3 (k0=kg*32).
// Lane owns j0, j0+64, j0+128 over a 32-wide k chunk: 96 weight floats in six
// f32x16 (static-indexed, asm-pinned). P partials 4-deep (was 8): gate reads
// 12 (was 24), P-writes 24 issues (was 48), barrier width 8 waves (was 16).
// gi (gamma*pd+r*pr+b_ih) + b_hh folded into kg==2 partials for r/z; bhh-only
// for n-slots (gi_n added by gate thread inside the r-multiplied term's sum).
__global__ __launch_bounds__(512, 1) void fused_kernel(
    const int* __restrict__ c_seq, const int* __restrict__ d_seq,
    const float* __restrict__ r_seq, const float* __restrict__ D_emb,
    const float* __restrict__ Whh, const float* __restrict__ bih,
    const float* __restrict__ bhh, const float* __restrict__ W2b,
    const float* __restrict__ b2a, const float* __restrict__ b2b,
    const float* __restrict__ ws, float* __restrict__ C_out,
    float* __restrict__ h_out)
{
    __shared__ __align__(16) float h_lds[VV];
    __shared__ float P[4][384];
    __shared__ __align__(16) float hist[16][VV];
    __shared__ float gam_row[TT], r_row[TT];
    __shared__ __align__(16) float C[KN];
    __shared__ int c_row[TT];

    int tid = threadIdx.x;

    if (blockIdx.x < BB) {
        // ================= GRU path =================
        int b = blockIdx.x;
        const float* pd = ws;
        const float* pr = ws + 384;
        int wid = tid >> 6, l = tid & 63;
        int jg = wid >> 2, kg = wid & 3;
        int j0 = jg * 192 + l;
        int k0 = kg * 32;

        if (tid < TT) {
            gam_row[tid] = D_emb[d_seq[b * TT + tid]];
            r_row[tid] = r_seq[b * TT + tid];
        }
        if (tid < VV) h_lds[tid] = 0.f;

        // 96 weight floats per thread: rows j0, j0+64, j0+128 x k[k0..k0+32)
        f32x16 w0a, w0b, w1a, w1b, w2a, w2b;
        {
            const float* p0 = Whh + (size_t)j0 * VV + k0;
            const float* p1 = Whh + (size_t)(j0 + 64) * VV + k0;
            const float* p2 = Whh + (size_t)(j0 + 128) * VV + k0;
            #define LD16(dst, src) { \
                float4 a_ = *(const float4*)(src); \
                float4 b_ = *(const float4*)((src) + 4); \
                float4 c_ = *(const float4*)((src) + 8); \
                float4 d_ = *(const float4*)((src) + 12); \
                dst[0] = a_.x;  dst[1] = a_.y;  dst[2] = a_.z;  dst[3] = a_.w; \
                dst[4] = b_.x;  dst[5] = b_.y;  dst[6] = b_.z;  dst[7] = b_.w; \
                dst[8] = c_.x;  dst[9] = c_.y;  dst[10] = c_.z; dst[11] = c_.w; \
                dst[12] = d_.x; dst[13] = d_.y; dst[14] = d_.z; dst[15] = d_.w; }
            LD16(w0a, p0)  LD16(w0b, p0 + 16)
            LD16(w1a, p1)  LD16(w1b, p1 + 16)
            LD16(w2a, p2)  LD16(w2b, p2 + 16)
            #undef LD16
        }

        // kg==2 gi/bias fold preloads (slots j0, j0+64, j0+128):
        // jg==0 -> all three < 256 (r/z): full fold. jg==1 -> slot0 in [192,256)
        // full fold; slots 1,2 >= 256 (n): bhh only.
        float apd0 = 0.f, apr0 = 0.f, ab0 = 0.f;
        float apd1 = 0.f, apr1 = 0.f, ab1 = 0.f;
        float apd2 = 0.f, apr2 = 0.f, ab2 = 0.f;
        if (kg == 2) {
            apd0 = pd[j0]; apr0 = pr[j0]; ab0 = bih[j0] + bhh[j0];
            if (jg == 0) {
                apd1 = pd[j0 + 64]; apr1 = pr[j0 + 64]; ab1 = bih[j0 + 64] + bhh[j0 + 64];
                apd2 = pd[j0 + 128]; apr2 = pr[j0 + 128]; ab2 = bih[j0 + 128] + bhh[j0 + 128];
            } else {
                ab1 = bhh[j0 + 64]; ab2 = bhh[j0 + 128];
            }
        }

        // gate-thread preloads (tid < 128): only the n-gate gi terms remain
        float pdn = 0.f, prn = 0.f, bin_ = 0.f;
        if (tid < VV) {
            pdn = pd[tid + 2 * VV]; prn = pr[tid + 2 * VV]; bin_ = bih[tid + 2 * VV];
        }
        __syncthreads();

        float* hp = h_out + (size_t)b * TT * VV;
        const float* hist_f = (const float*)hist;

        for (int t = 0; t < TT; ++t) {
            // pin weights across the back-edge (forbid remat-from-memory)
            asm volatile("" : "+v"(w0a), "+v"(w0b), "+v"(w1a), "+v"(w1b), "+v"(w2a), "+v"(w2b));
            // ---- matvec: uniform-address LDS broadcast of the 32-wide h chunk ----
            float4 hv0 = *(const float4*)&h_lds[k0];
            float4 hv1 = *(const float4*)&h_lds[k0 + 4];
            float4 hv2 = *(const float4*)&h_lds[k0 + 8];
            float4 hv3 = *(const float4*)&h_lds[k0 + 12];
            float4 hv4 = *(const float4*)&h_lds[k0 + 16];
            float4 hv5 = *(const float4*)&h_lds[k0 + 20];
            float4 hv6 = *(const float4*)&h_lds[k0 + 24];
            float4 hv7 = *(const float4*)&h_lds[k0 + 28];
            float a0 = 0.f, a1 = 0.f, a2 = 0.f;
            #define FSTEP(va, vb, i, hval) \
                a0 = fmaf(hval, w0##va[i], a0); a1 = fmaf(hval, w1##va[i], a1); a2 = fmaf(hval, w2##va[i], a2);
            FSTEP(a,, 0, hv0.x)  FSTEP(a,, 1, hv0.y)  FSTEP(a,, 2, hv0.z)  FSTEP(a,, 3, hv0.w)
            FSTEP(a,, 4, hv1.x)  FSTEP(a,, 5, hv1.y)  FSTEP(a,, 6, hv1.z)  FSTEP(a,, 7, hv1.w)
            FSTEP(a,, 8, hv2.x)  FSTEP(a,, 9, hv2.y)  FSTEP(a,, 10, hv2.z) FSTEP(a,, 11, hv2.w)
            FSTEP(a,, 12, hv3.x) FSTEP(a,, 13, hv3.y) FSTEP(a,, 14, hv3.z) FSTEP(a,, 15, hv3.w)
            FSTEP(b,, 0, hv4.x)  FSTEP(b,, 1, hv4.y)  FSTEP(b,, 2, hv4.z)  FSTEP(b,, 3, hv4.w)
            FSTEP(b,, 4, hv5.x)  FSTEP(b,, 5, hv5.y)  FSTEP(b,, 6, hv5.z)  FSTEP(b,, 7, hv5.w)
            FSTEP(b,, 8, hv6.x)  FSTEP(b,, 9, hv6.y)  FSTEP(b,, 10, hv6.z) FSTEP(b,, 11, hv6.w)
            FSTEP(b,, 12, hv7.x) FSTEP(b,, 13, hv7.y) FSTEP(b,, 14, hv7.z) FSTEP(b,, 15, hv7.w)
            #undef FSTEP
            if (kg == 2) {
                float g = gam_row[t], rr = r_row[t];
                a0 += fmaf(g, apd0, fmaf(rr, apr0, ab0));
                if (jg == 0) {
                    a1 += fmaf(g, apd1, fmaf(rr, apr1, ab1));
                    a2 += fmaf(g, apd2, fmaf(rr, apr2, ab2));
                } else {
                    a1 += ab1;
                    a2 += ab2;
                }
            }
            P[kg][j0] = a0;
            P[kg][j0 + 64] = a1;
            P[kg][j0 + 128] = a2;
            __syncthreads();

            // ---- gates on threads <128; history flush on the rest ----
            if (tid < VV) {
                int n = tid;
                float ghr = (P[0][n] + P[1][n]) + (P[2][n] + P[3][n]);
                int nz = n + 128;
                float ghz = (P[0][nz] + P[1][nz]) + (P[2][nz] + P[3][nz]);
                int nn2 = n + 256;
                float ghn = (P[0][nn2] + P[1][nn2]) + (P[2][nn2] + P[3][nn2]);
                float g = gam_row[t], rr = r_row[t];
                float r = sigm(ghr);
                float z = sigm(ghz);
                float gin = fmaf(g, pdn, fmaf(rr, prn, bin_));
                float nn = tanh_f(fmaf(r, ghn, gin));
                float h = h_lds[n];
                float hn = fmaf(1.f - z, nn, z * h);
                h_lds[n] = hn;
                hist[t & 15][n] = hn;
            } else if ((t & 7) == 0 && t > 0) {
                int t0 = t - 8;                     // flush slots (t-8..t-1)&15
                int s0 = t0 & 15;                   // contiguous 8-slot group
                for (int i = tid - 128; i < 8 * VV; i += 384)
                    hp[t0 * VV + i] = hist_f[s0 * VV + i];
            }
            __syncthreads();
        }
        // final 8 steps (t = 192..199 -> slots 0..7)
        for (int i = tid; i < 8 * VV; i += 512)
            hp[192 * VV + i] = hist_f[i];
    } else {
        // ================= memory-scan path (single wave) =================
        int b = blockIdx.x - BB;
        const float* uc = ws + 768;
        const float* ud = ws + 896;
        const float* ur = ws + 1024;
        for (int i = tid; i < KN; i += 512) C[i] = 0.f;
        if (tid < TT) {
            gam_row[tid] = D_emb[d_seq[b * TT + tid]];
            r_row[tid] = r_seq[b * TT + tid];
            c_row[tid] = c_seq[b * TT + tid];
        }
        __syncthreads();
        if (tid >= 64) return;
        int l = tid;
        float uc0 = uc[l], uc1 = uc[l + 64];
        float ud0 = ud[l], ud1 = ud[l + 64];
        float ur0 = ur[l], ur1 = ur[l + 64];
        float ba0 = b2a[l], ba1 = b2a[l + 64];
        float wb0 = W2b[l], wb1 = W2b[l + 64];
        float bb = b2b[0];
        float* cop = C_out + (size_t)b * TT * KN;
        for (int t = 0; t < TT; ++t) {
            int ct = c_row[t];
            float beta = C[ct];
            float g = gam_row[t], rr = r_row[t];
            float h0 = fmaxf(fmaf(beta, uc0, fmaf(g, ud0, fmaf(rr, ur0, ba0))), 0.f);
            float h1 = fmaxf(fmaf(beta, uc1, fmaf(g, ud1, fmaf(rr, ur1, ba1))), 0.f);
            float p = fmaf(h0, wb0, h1 * wb1);
            #pragma unroll
            for (int m = 32; m > 0; m >>= 1) p += __shfl_xor(p, m);
            float nc = p + bb;
            if (l == 0) C[ct] = nc;
            float* rowp = cop + (size_t)t * KN;
            #pragma unroll
            for (int s = 0; s < 8; ++s) {
                int idx = 256 * s + 4 * l;
                if (s < 7 || l < 52) {
                    float4 v = *(const float4*)&C[idx];
                    *(float4*)&rowp[idx] = v;
                }
            }
        }
    }
}

// ---------------- alpha head: bf16 MFMA, fragments loaded straight from global -
__device__ __forceinline__ short f2bf(float f) {
    uint32_t u = __float_as_uint(f);
    u = (u + 0x7FFFu + ((u >> 16) & 1u)) >> 16;
    return (short)u;
}
__device__ __forceinline__ bf16x8 load_cvt8(const float* p) {
    float4 a = *(const float4*)p;
    float4 c = *(const float4*)(p + 4);
    bf16x8 r;
    r[0] = f2bf(a.x); r[1] = f2bf(a.y); r[2] = f2bf(a.z); r[3] = f2bf(a.w);
    r[4] = f2bf(c.x); r[5] = f2bf(c.y); r[6] = f2bf(c.z); r[7] = f2bf(c.w);
    return r;
}

__global__ void alpha_kernel(const float* __restrict__ h_seq, const float* __restrict__ W1a,
                             const float* __restrict__ b1a, const float* __restrict__ W1b,
                             const float* __restrict__ b1b, float* __restrict__ alpha)
{
    int wave = threadIdx.x >> 6;
    int lane = threadIdx.x & 63;
    int tile = blockIdx.x * 4 + wave;  // 800 tiles of 16 rows
    int rowbase = tile * 16;
    int rl = lane & 15, g = lane >> 4;
    const float* hp = h_seq + (size_t)(rowbase + rl) * VV + g * 8;
    bf16x8 a0 = load_cvt8(hp);
    bf16x8 a1 = load_cvt8(hp + 32);
    bf16x8 a2 = load_cvt8(hp + 64);
    bf16x8 a3 = load_cvt8(hp + 96);
    float p0 = 0.f, p1 = 0.f, p2 = 0.f, p3 = 0.f;
    float bb = b1b[0];
    #pragma unroll
    for (int jt = 0; jt < 8; ++jt) {
        int j = jt * 16 + rl;
        const float* wp = W1a + (size_t)j * VV + g * 8;
        f32x4 acc = {0.f, 0.f, 0.f, 0.f};
        acc = __builtin_amdgcn_mfma_f32_16x16x32_bf16(a0, load_cvt8(wp), acc, 0, 0, 0);
        acc = __builtin_amdgcn_mfma_f32_16x16x32_bf16(a1, load_cvt8(wp + 32), acc, 0, 0, 0);
        acc = __builtin_amdgcn_mfma_f32_16x16x32_bf16(a2, load_cvt8(wp + 64), acc, 0, 0, 0);
        acc = __builtin_amdgcn_mfma_f32_16x16x32_bf16(a3, load_cvt8(wp + 96), acc, 0, 0, 0);
        float bj = b1a[j], wj = W1b[j];
        p0 += fmaxf(acc[0] + bj, 0.f) * wj;
        p1 += fmaxf(acc[1] + bj, 0.f) * wj;
        p2 += fmaxf(acc[2] + bj, 0.f) * wj;
        p3 += fmaxf(acc[3] + bj, 0.f) * wj;
    }
    #pragma unroll
    for (int m = 1; m < 16; m <<= 1) {
        p0 += __shfl_xor(p0, m);
        p1 += __shfl_xor(p1, m);
        p2 += __shfl_xor(p2, m);
        p3 += __shfl_xor(p3, m);
    }
    if (rl == 0) {
        alpha[rowbase + g * 4 + 0] = p0 + bb;
        alpha[rowbase + g * 4 + 1] = p1 + bb;
        alpha[rowbase + g * 4 + 2] = p2 + bb;
        alpha[rowbase + g * 4 + 3] = p3 + bb;
    }
}

extern "C" void kernel_launch(void* const* d_in, const int* in_sizes, int n_in,
                              void* d_out, int out_size, void* d_ws, size_t ws_size,
                              hipStream_t stream)
{
    const int*   c_seq = (const int*)d_in[0];
    const int*   d_seq = (const int*)d_in[1];
    const float* r_seq = (const float*)d_in[2];
    const float* D_emb = (const float*)d_in[3];
    const float* v_d   = (const float*)d_in[4];
    const float* v_r   = (const float*)d_in[5];
    const float* v_c   = (const float*)d_in[6];
    const float* W_ih  = (const float*)d_in[7];
    const float* W_hh  = (const float*)d_in[8];
    const float* b_ih  = (const float*)d_in[9];
    const float* b_hh  = (const float*)d_in[10];
    const float* W1a   = (const float*)d_in[11];
    const float* b1a   = (const float*)d_in[12];
    const float* W1b   = (const float*)d_in[13];
    const float* b1b   = (const float*)d_in[14];
    const float* W2a   = (const float*)d_in[15];
    const float* b2a   = (const float*)d_in[16];
    const float* W2b   = (const float*)d_in[17];
    const float* b2b   = (const float*)d_in[18];

    float* out   = (float*)d_out;
    float* alpha = out;                       // 12800
    float* h_seq = out + 12800;               // 1,638,400
    float* C_out = out + 12800 + 1638400;     // 25,600,000
    float* ws    = (float*)d_ws;

    hipLaunchKernelGGL(pre_kernel, dim3(2), dim3(256), 0, stream,
                       v_d, v_r, v_c, W_ih, W2a, ws);
    hipLaunchKernelGGL(fused_kernel, dim3(BB * 2), dim3(512), 0, stream,
                       c_seq, d_seq, r_seq, D_emb, W_hh, b_ih, b_hh,
                       W2b, b2a, b2b, ws, C_out, h_seq);
    hipLaunchKernelGGL(alpha_kernel, dim3(200), dim3(256), 0, stream,
                       h_seq, W1a, b1a, W1b, b1b, alpha);
}